// Round 2
// baseline (902.680 us; speedup 1.0000x reference)
//
#include <hip/hip_runtime.h>
#include <hip/hip_bf16.h>

// GlobalAggregator: B=256, N=256, K=16, DIM=128
//   gated = extra[:,:,None,:] * neighbor                  [B,N,K,128]
//   alpha = gated @ w1[:128] + weight[...,None]*w1[128]   [B,N,K,128]
//   alpha = leaky_relu(alpha, 0.2) @ w2                   [B,N,K]
//   alpha = softmax(alpha, axis=K)
//   out   = sum_k alpha * neighbor                        [B,N,128]
//
// v2: bf16 MFMA core (verified R1, absmax 7.8e-3). Epilogue rebuilt:
//  - 16-lane m-reduce via DPP (quad_perm xor1/xor2 + row_ror:4/8), VALU pipe
//  - z gathered to all lanes with 12 swizzles depth-2, softmax fully in-lane
//  - bias/w2 hoisted to registers; normalize folded into final scale
//  - no per-iteration break -> position loop can pipeline

#define KN 16
#define DIM 128
#define POS_PER_WAVE 8
#define WAVES_PER_BLOCK 4

typedef __bf16 bf16_t;
typedef bf16_t bf16x8 __attribute__((ext_vector_type(8)));
typedef float f32x4 __attribute__((ext_vector_type(4)));

template <int CTRL>
__device__ __forceinline__ float dpp_mov_f32(float x) {
    return __int_as_float(__builtin_amdgcn_update_dpp(
        0, __float_as_int(x), CTRL, 0xF, 0xF, true));
}

// Butterfly sum across the 16-lane row; every lane ends with the row total.
__device__ __forceinline__ float row16_sum(float v) {
    v += dpp_mov_f32<0xB1>(v);   // quad_perm [1,0,3,2]  (xor 1)
    v += dpp_mov_f32<0x4E>(v);   // quad_perm [2,3,0,1]  (xor 2)
    v += dpp_mov_f32<0x124>(v);  // row_ror:4
    v += dpp_mov_f32<0x128>(v);  // row_ror:8
    return v;
}

__device__ __forceinline__ void process_pos(
    const float* __restrict__ nb,   // [16][128] this position's neighbors
    const float* __restrict__ ex,   // [128]
    const float* __restrict__ wt,   // [16]
    float* __restrict__ outp,       // [128]
    const bf16x8* __restrict__ bfrag_lds,
    const float* __restrict__ bias_r,  // [8] per-lane col m
    const float* __restrict__ w2_r,    // [8]
    int lane, int q, int m)
{
    f32x4 wt4 = *(const f32x4*)(wt + q * 4);   // wt[k], k = q*4+r

    // A[m][k = ik*32 + q*8 + j] = ex[c] * nb[m][c]
    bf16x8 afrag[4];
    #pragma unroll
    for (int ik = 0; ik < 4; ++ik) {
        const int c = ik * 32 + q * 8;
        f32x4 ex0 = *(const f32x4*)(ex + c);
        f32x4 ex1 = *(const f32x4*)(ex + c + 4);
        f32x4 nb0 = *(const f32x4*)(nb + m * DIM + c);
        f32x4 nb1 = *(const f32x4*)(nb + m * DIM + c + 4);
        #pragma unroll
        for (int j = 0; j < 4; ++j) {
            afrag[ik][j]     = (bf16_t)(ex0[j] * nb0[j]);
            afrag[ik][j + 4] = (bf16_t)(ex1[j] * nb1[j]);
        }
    }

    f32x4 acc[8];
    #pragma unroll
    for (int e0 = 0; e0 < 8; ++e0) acc[e0] = (f32x4){0.f, 0.f, 0.f, 0.f};
    #pragma unroll
    for (int e0 = 0; e0 < 8; ++e0) {
        #pragma unroll
        for (int ik = 0; ik < 4; ++ik) {
            acc[e0] = __builtin_amdgcn_mfma_f32_16x16x32_bf16(
                afrag[ik], bfrag_lds[(e0 * 4 + ik) * 64 + lane], acc[e0],
                0, 0, 0);
        }
    }

    // z[r] for k=q*4+r: leaky_relu(acc + wt*bias) . w2, summed over e
    // (in-lane over e0 blocks, DPP butterfly over the 16 m-lanes)
    float z[4];
    #pragma unroll
    for (int r = 0; r < 4; ++r) {
        float s = 0.f;
        #pragma unroll
        for (int e0 = 0; e0 < 8; ++e0) {
            float a = acc[e0][r] + wt4[r] * bias_r[e0];
            a = fmaxf(a, 0.2f * a);            // leaky_relu(0.2)
            s += a * w2_r[e0];
        }
        z[r] = row16_sum(s);
    }

    // Gather all 16 z per lane: zs[s][r] = z for k = 4*(q^s)+r  (depth 2)
    float zs[4][4];
    #pragma unroll
    for (int r = 0; r < 4; ++r) {
        zs[0][r] = z[r];
        zs[1][r] = __shfl_xor(z[r], 16, 64);
    }
    #pragma unroll
    for (int r = 0; r < 4; ++r) {
        zs[2][r] = __shfl_xor(zs[0][r], 32, 64);
        zs[3][r] = __shfl_xor(zs[1][r], 32, 64);
    }

    // In-lane softmax (unnormalized; scale folded into the output)
    float mx = zs[0][0];
    #pragma unroll
    for (int s = 0; s < 4; ++s)
        #pragma unroll
        for (int r = 0; r < 4; ++r) mx = fmaxf(mx, zs[s][r]);
    float al[4][4];
    float den = 0.f;
    #pragma unroll
    for (int s = 0; s < 4; ++s)
        #pragma unroll
        for (int r = 0; r < 4; ++r) {
            al[s][r] = __expf(zs[s][r] - mx);
            den += al[s][r];
        }
    const float inv = 1.f / den;

    // out[d] = inv * sum_k e_k * nb[k][d]; lane owns d = 2*lane, 2*lane+1
    const int d0 = lane * 2;
    float ox = 0.f, oy = 0.f;
    #pragma unroll
    for (int s = 0; s < 4; ++s) {
        const float* nbk = nb + ((q ^ s) * 4) * DIM + d0;  // k = 4*(q^s)+r
        #pragma unroll
        for (int r = 0; r < 4; ++r) {
            float2 v = *(const float2*)(nbk + r * DIM);
            ox += al[s][r] * v.x;
            oy += al[s][r] * v.y;
        }
    }
    float2 o = {ox * inv, oy * inv};
    *(float2*)(outp + d0) = o;
}

__global__ __launch_bounds__(256) void agg_kernel(
    const float* __restrict__ nb_g,   // [POS][16][128]
    const float* __restrict__ wt_g,   // [POS][16]
    const float* __restrict__ ex_g,   // [POS][128]
    const float* __restrict__ w1_g,   // [129][128]
    const float* __restrict__ w2_g,   // [128]
    float* __restrict__ out_g,        // [POS][128]
    int pos_total)
{
    // B fragments of w1[:128] packed per-lane: index (e0*4+ik)*64+lane holds
    // 8 bf16 = w1[ik*32+q*8+j][e0*16+m]; lane-contiguous 16B -> conflict-free
    // ds_read_b128. (Layout verified correct in R1.)
    __shared__ bf16x8 bfrag_lds[8 * 4 * 64];   // 32 KB

    const int t = threadIdx.x;
    #pragma unroll
    for (int f0 = 0; f0 < 8; ++f0) {
        int f = f0 * 256 + t;
        int e0   = f >> 8;
        int ik   = (f >> 6) & 3;
        int lane = f & 63;
        int qq = lane >> 4, mm = lane & 15;
        bf16x8 v;
        #pragma unroll
        for (int j = 0; j < 8; ++j) {
            int d = ik * 32 + qq * 8 + j;
            v[j] = (bf16_t)w1_g[d * DIM + e0 * 16 + mm];
        }
        bfrag_lds[f] = v;
    }
    __syncthreads();

    const int wave = t >> 6;
    const int lane = t & 63;
    const int q = lane >> 4;    // 0..3
    const int m = lane & 15;    // 0..15

    // bias/w2 for this lane's columns, hoisted across all positions
    float bias_r[8], w2_r[8];
    #pragma unroll
    for (int e0 = 0; e0 < 8; ++e0) {
        bias_r[e0] = w1_g[128 * DIM + e0 * 16 + m];
        w2_r[e0]   = w2_g[e0 * 16 + m];
    }

    const long wave_global = (long)blockIdx.x * WAVES_PER_BLOCK + wave;
    const long p0 = wave_global * POS_PER_WAVE;

    if (p0 + POS_PER_WAVE <= pos_total) {
        #pragma unroll
        for (int it = 0; it < POS_PER_WAVE; ++it) {
            const long p = p0 + it;
            process_pos(nb_g + p * (KN * DIM), ex_g + p * DIM, wt_g + p * KN,
                        out_g + p * DIM, bfrag_lds, bias_r, w2_r, lane, q, m);
        }
    } else {
        for (long p = p0; p < pos_total; ++p) {
            process_pos(nb_g + p * (KN * DIM), ex_g + p * DIM, wt_g + p * KN,
                        out_g + p * DIM, bfrag_lds, bias_r, w2_r, lane, q, m);
        }
    }
}

extern "C" void kernel_launch(void* const* d_in, const int* in_sizes, int n_in,
                              void* d_out, int out_size, void* d_ws, size_t ws_size,
                              hipStream_t stream) {
    // inputs (setup_inputs order):
    // 0 self_vectors (unused), 1 neighbor_vector, 2 batch_size (unused),
    // 3 masks (unused), 4 neighbor_weight, 5 extra_vector, 6 w_1, 7 w_2
    const float* nb = (const float*)d_in[1];
    const float* wt = (const float*)d_in[4];
    const float* ex = (const float*)d_in[5];
    const float* w1 = (const float*)d_in[6];
    const float* w2 = (const float*)d_in[7];
    float* out = (float*)d_out;

    const int pos_total = in_sizes[5] / DIM;                  // B*N = 65536
    const long waves = ((long)pos_total + POS_PER_WAVE - 1) / POS_PER_WAVE;
    const int blocks = (int)((waves + WAVES_PER_BLOCK - 1) / WAVES_PER_BLOCK);

    agg_kernel<<<blocks, 256, 0, stream>>>(nb, wt, ex, w1, w2, out, pos_total);
}